// Round 1
// baseline (529.662 us; speedup 1.0000x reference)
//
#include <hip/hip_runtime.h>

// out (176, 192, 56, 56) fp32:
//   out[:, :64]  = x (176, 64, 56, 56)
//   out[:, 64:]  = y (176, 128, 28, 28) nearest-upsampled x2
// Pure HBM-bound: ~636 MB moved -> ~101 us floor at 6.3 TB/s.

#define NB   176
#define C1   64
#define C2   128
#define HH   56
#define WW   56
#define H2   28
#define W2   28
#define CT   (C1 + C2)          // 192
#define VPR  (WW / 4)           // 14 float4 per output row
#define NROWS (NB * CT * HH)    // 1,892,352 rows
#define NVEC  (NROWS * VPR)     // 26,492,928 float4 stores

__global__ __launch_bounds__(256) void upcat_kernel(
    const float* __restrict__ x,
    const float* __restrict__ y,
    float* __restrict__ out)
{
    int i = blockIdx.x * blockDim.x + threadIdx.x;
    if (i >= NVEC) return;

    int r  = i / VPR;            // output row id: (b, c, h)
    int j  = i - r * VPR;        // float4 slot within row
    int w0 = j * 4;

    int h  = r % HH;
    int bc = r / HH;
    int c  = bc % CT;
    int b  = bc / CT;

    float4 v;
    if (c < C1) {
        // straight copy from x, 16B-aligned (w0 % 4 == 0)
        const float4* px = (const float4*)(x + ((b * C1 + c) * HH + h) * WW + w0);
        v = *px;
    } else {
        // nearest upsample: out[w0..w0+3] = y[w0/2], y[w0/2], y[w0/2+1], y[w0/2+1]
        int c2 = c - C1;
        const float2* py = (const float2*)(y + ((b * C2 + c2) * H2 + (h >> 1)) * W2 + (w0 >> 1));
        float2 u = *py;
        v = make_float4(u.x, u.x, u.y, u.y);
    }

    float4* po = (float4*)(out + r * WW + w0);
    *po = v;
}

extern "C" void kernel_launch(void* const* d_in, const int* in_sizes, int n_in,
                              void* d_out, int out_size, void* d_ws, size_t ws_size,
                              hipStream_t stream) {
    const float* x = (const float*)d_in[0];
    const float* y = (const float*)d_in[1];
    float* out = (float*)d_out;

    int nblocks = (NVEC + 255) / 256;
    upcat_kernel<<<nblocks, 256, 0, stream>>>(x, y, out);
}